// Round 1
// baseline (432.758 us; speedup 1.0000x reference)
//
#include <hip/hip_runtime.h>
#include <math.h>

// CapsuleLayer dynamic routing, fp32, MI355X.
// B=64, IN_CAPS=2048, IN_DIM=8, OUT_CAPS=32, OUT_DIM=16, 3 routing iters.
//
// Identity used: b_ij after r rounds of updates = u_hat_i . (v0+...+v_{r-1})
// since b starts at zero. So no u_hat materialization and no b_ij storage:
// each pass recomputes u_hat_i from W (8 MB) and x (4 MB), which stay
// L2/LLC resident. 3 passes + 3 tiny squash kernels + 1 memset.

#define IN_CAPS_N  2048
#define IN_DIM_N   8
#define OUT_CAPS_N 32
#define OUT_DIM_N  16
#define BATCH_N    64
#define S_ELEMS    (BATCH_N * OUT_CAPS_N * OUT_DIM_N)   // 32768 floats

#define NB 4                       // batch elements per wave (W-register reuse)
#define BG (BATCH_N / NB)          // 16 batch groups
#define IS 64                      // i-stripes
#define I_PER_BLOCK (IN_CAPS_N / IS)   // 32
#define I_PER_WAVE  (I_PER_BLOCK / 4)  // 8

// One wave handles (bgroup of 4 b's) x (8 i's). Lane -> (o = lane&31,
// j-half = lane>>5, 8 j's each). Softmax over the 32 o's is a pure in-wave
// butterfly: lanes l and l^32 first combine j-halves, then 5-step xor
// reduction over the 32-lane group. No __syncthreads in the hot loop.
template <int FIRST>
__launch_bounds__(256, 3)
__global__ void caps_pass_kernel(const float* __restrict__ W,
                                 const float* __restrict__ x,
                                 const float* __restrict__ vsum,
                                 float* __restrict__ s_out)
{
    const int tid  = threadIdx.x;
    const int lane = tid & 63;
    const int wid  = tid >> 6;      // wave in block, 0..3
    const int o    = lane & 31;
    const int jh   = lane >> 5;     // j-half: j = jh*8 + jj

    const int bg      = blockIdx.x & (BG - 1);  // consecutive blocks share W window
    const int istripe = blockIdx.x / BG;
    const int b0      = bg * NB;

    float acc[NB][8];
#pragma unroll
    for (int n = 0; n < NB; ++n)
#pragma unroll
        for (int jj = 0; jj < 8; ++jj) acc[n][jj] = 0.0f;

    for (int k = 0; k < I_PER_WAVE; ++k) {
        const int i = istripe * I_PER_BLOCK + wid + 4 * k;  // waves interleave i's

        // W[i, o, jh*8 .. jh*8+7, 0..7] : 64 contiguous floats per lane
        const float4* wp =
            (const float4*)(W + (((size_t)i * OUT_CAPS_N + o) * OUT_DIM_N + jh * 8) * IN_DIM_N);
        float4 w[16];
#pragma unroll
        for (int q = 0; q < 16; ++q) w[q] = wp[q];

#pragma unroll
        for (int n = 0; n < NB; ++n) {
            const int b = b0 + n;
            const float4* xp = (const float4*)(x + ((size_t)b * IN_CAPS_N + i) * IN_DIM_N);
            const float4 xa = xp[0];
            const float4 xb = xp[1];

            float u[8];
#pragma unroll
            for (int jj = 0; jj < 8; ++jj) {
                const float4 wa = w[2 * jj];
                const float4 wb = w[2 * jj + 1];
                float t = wa.x * xa.x;
                t = fmaf(wa.y, xa.y, t);
                t = fmaf(wa.z, xa.z, t);
                t = fmaf(wa.w, xa.w, t);
                t = fmaf(wb.x, xb.x, t);
                t = fmaf(wb.y, xb.y, t);
                t = fmaf(wb.z, xb.z, t);
                t = fmaf(wb.w, xb.w, t);
                u[jj] = t;
            }

            float c;
            if (FIRST) {
                c = 1.0f;  // uniform softmax(0)=1/32 applied at the final scale
            } else {
                // b_io = sum_j u[o,j] * vsum[b,o,j]
                const float4* vp =
                    (const float4*)(vsum + ((size_t)b * OUT_CAPS_N + o) * OUT_DIM_N + jh * 8);
                const float4 va = vp[0];
                const float4 vb = vp[1];
                float bp = u[0] * va.x;
                bp = fmaf(u[1], va.y, bp);
                bp = fmaf(u[2], va.z, bp);
                bp = fmaf(u[3], va.w, bp);
                bp = fmaf(u[4], vb.x, bp);
                bp = fmaf(u[5], vb.y, bp);
                bp = fmaf(u[6], vb.z, bp);
                bp = fmaf(u[7], vb.w, bp);
                bp += __shfl_xor(bp, 32);   // combine the two j-halves

                // softmax over 32 o's (lanes 0..31, mirrored in 32..63)
                float m = bp;
                m = fmaxf(m, __shfl_xor(m, 16));
                m = fmaxf(m, __shfl_xor(m, 8));
                m = fmaxf(m, __shfl_xor(m, 4));
                m = fmaxf(m, __shfl_xor(m, 2));
                m = fmaxf(m, __shfl_xor(m, 1));
                const float e = __expf(bp - m);
                float se = e;
                se += __shfl_xor(se, 16);
                se += __shfl_xor(se, 8);
                se += __shfl_xor(se, 4);
                se += __shfl_xor(se, 2);
                se += __shfl_xor(se, 1);
                c = e / se;
            }

#pragma unroll
            for (int jj = 0; jj < 8; ++jj) acc[n][jj] = fmaf(c, u[jj], acc[n][jj]);
        }
    }

    // Block reduction over the 4 waves (same b-group -> same s addresses),
    // then one atomicAdd per element: 2048 atomics/block, 2M/pass total.
    __shared__ float red[4][NB * 512];
    const int slot = o * 16 + jh * 8;
#pragma unroll
    for (int n = 0; n < NB; ++n)
#pragma unroll
        for (int jj = 0; jj < 8; ++jj)
            red[wid][n * 512 + slot + jj] = acc[n][jj];
    __syncthreads();

    const float scale = FIRST ? (1.0f / 32.0f) : 1.0f;
#pragma unroll
    for (int idx = tid; idx < NB * 512; idx += 256) {
        const float v = red[0][idx] + red[1][idx] + red[2][idx] + red[3][idx];
        const int n  = idx >> 9;
        const int oj = idx & 511;
        atomicAdd(&s_out[(size_t)(b0 + n) * 512 + oj], v * scale);
    }
}

// squash per (b,o) row of 16; rows are 16-lane groups inside a wave.
// MODE 0: vsum = v   MODE 1: vsum += v   MODE 2: out = v
template <int MODE>
__global__ void squash_kernel(const float* __restrict__ s_in,
                              float* __restrict__ vsum,
                              float* __restrict__ out)
{
    const int idx = blockIdx.x * 256 + threadIdx.x;  // 0..32767
    const float sv = s_in[idx];
    float s2 = sv * sv;
    s2 += __shfl_xor(s2, 1);
    s2 += __shfl_xor(s2, 2);
    s2 += __shfl_xor(s2, 4);
    s2 += __shfl_xor(s2, 8);
    const float v = sv * (s2 / ((1.0f + s2) * sqrtf(s2 + 1e-9f)));
    if (MODE == 0)      vsum[idx] = v;
    else if (MODE == 1) vsum[idx] += v;
    else                out[idx]  = v;
}

extern "C" void kernel_launch(void* const* d_in, const int* in_sizes, int n_in,
                              void* d_out, int out_size, void* d_ws, size_t ws_size,
                              hipStream_t stream)
{
    const float* x = (const float*)d_in[0];   // [64, 2048, 8]
    const float* W = (const float*)d_in[1];   // [1, 2048, 32, 16, 8]
    float* out = (float*)d_out;               // [64, 32, 16]

    float* s0   = (float*)d_ws;               // 3 s-buffers + running v-sum
    float* s1   = s0 + S_ELEMS;
    float* s2   = s1 + S_ELEMS;
    float* vsum = s2 + S_ELEMS;

    // s-buffers must start at zero every call (ws is re-poisoned by harness)
    hipMemsetAsync(d_ws, 0, (size_t)3 * S_ELEMS * sizeof(float), stream);

    const dim3 grid(BG * IS);   // 1024 blocks
    const dim3 blk(256);
    const dim3 sgrid(S_ELEMS / 256);  // 128 blocks

    // round 0: c uniform
    caps_pass_kernel<1><<<grid, blk, 0, stream>>>(W, x, nullptr, s0);
    squash_kernel<0><<<sgrid, blk, 0, stream>>>(s0, vsum, out);   // vsum = v0
    // round 1: b = u.v0
    caps_pass_kernel<0><<<grid, blk, 0, stream>>>(W, x, vsum, s1);
    squash_kernel<1><<<sgrid, blk, 0, stream>>>(s1, vsum, out);   // vsum = v0+v1
    // round 2: b = u.(v0+v1)
    caps_pass_kernel<0><<<grid, blk, 0, stream>>>(W, x, vsum, s2);
    squash_kernel<2><<<sgrid, blk, 0, stream>>>(s2, vsum, out);   // out = v2
}

// Round 2
// 180.165 us; speedup vs baseline: 2.4020x; 2.4020x over previous
//
#include <hip/hip_runtime.h>
#include <math.h>

// CapsuleLayer dynamic routing, fp32, MI355X (gfx950).
// B=64, IN_CAPS=2048, IN_DIM=8, OUT_CAPS=32, OUT_DIM=16, 3 routing iters.
//
// b_ij after r updates = u_hat_i . (v0+...+v_{r-1})  (b starts at 0), so no
// u_hat materialization: each pass recomputes u_hat from W via LDS staging.
//
// R1 -> R2: round-1 was latency-bound (VALUBusy 14.6%): per-lane 256 B W
// gathers scattered every dwordx4 over 64 cache lines and thrashed L1
// (256 KB working set vs 32 KB). Now W is staged global->LDS coalesced
// (double-buffered, block-synchronous i-loop), deswizzled into two padded
// regions so hot-loop ds_read_b128 is conflict-optimal. Atomics removed:
// blocks write disjoint 16 MB partials; squash kernel fuses the reduction.
// Softmax max-step dropped (logits bounded; exp safe in fp32).

#define IC 2048
#define ID 8
#define OC 32
#define OD 16
#define B_N 64
#define S_ELEMS (B_N * OC * OD)   // 32768
#define IB 16                     // i's per block
#define ISTR (IC / IB)            // 128 i-stripes
#define BPB 16                    // b's per block
#define BG (B_N / BPB)            // 4 b-groups
#define ROWQ 65                   // float4 row stride (64 + 1 pad)
#define NREG (8 * ROWQ)           // float4s per W region per parity

// Lane map: o = lane&31, jh = lane>>5 (j = jh*8 + jj). Softmax over the 32
// o's is an in-wave butterfly; jh-halves combine via shfl_xor(.,32).
// W tile i (4096 floats, [o][j][d]) is stored in LDS as two regions:
//   WA[jj][c] = W[o][jh*8+jj][0..3], WB[jj][c] = W[o][jh*8+jj][4..7]
// with c = (o<<1)|jh. For fixed jj, lanes read 64 distinct consecutive-ish
// float4s (stride-1 bank profile). ROWQ=65 padding also spreads the
// staging-write banks.

template <int FIRST>
__launch_bounds__(256, 2)
__global__ void caps_pass(const float* __restrict__ Wg,
                          const float* __restrict__ xg,
                          const float* __restrict__ vs,
                          float* __restrict__ part)
{
    __shared__ float4 WA[2][NREG];
    __shared__ float4 WB[2][NREG];
    __shared__ float4 xs[2][BPB * 2];

    const int tid  = threadIdx.x;
    const int lane = tid & 63;
    const int w    = tid >> 6;        // wave 0..3
    const int o    = lane & 31;
    const int jh   = lane >> 5;
    const int c    = (o << 1) | jh;   // lane's W chunk, a permutation of 0..63

    const int is   = blockIdx.x & (ISTR - 1);  // same-W blocks are 128 apart
    const int bg   = blockIdx.x >> 7;          // -> land on the same XCD
    const int bblk = bg * BPB;
    const int bw   = bblk + w * 4;             // this wave's 4 b's

    const float4* wq = (const float4*)Wg;

    // swizzled scatter of one staged float4 into the WA/WB regions
    auto put = [&](int parity, int Q, float4 v) {
        const int cw = Q >> 4;      // chunk 0..63
        const int qq = Q & 15;      // quad within chunk
        float4* dst = (qq & 1) ? &WB[parity][(qq >> 1) * ROWQ + cw]
                               : &WA[parity][(qq >> 1) * ROWQ + cw];
        *dst = v;
    };

    // routing coefficients' v-sum fragment, held in registers across i-loop
    float4 va[4], vb[4];
    if (!FIRST) {
#pragma unroll
        for (int n = 0; n < 4; ++n) {
            const float4* vp =
                (const float4*)(vs + (size_t)(bw + n) * (OC * OD) + o * OD + jh * 8);
            va[n] = vp[0];
            vb[n] = vp[1];
        }
    }

    float acc[4][8];
#pragma unroll
    for (int n = 0; n < 4; ++n)
#pragma unroll
        for (int jj = 0; jj < 8; ++jj) acc[n][jj] = 0.0f;

    // ---- prologue: stage tile 0 (parity 0): W 16 KB coalesced + x 512 B
    {
        const int ig = is * IB;
        const size_t wb0 = (size_t)ig * 1024;
        float4 g0 = wq[wb0 + 0 * 256 + tid];
        float4 g1 = wq[wb0 + 1 * 256 + tid];
        float4 g2 = wq[wb0 + 2 * 256 + tid];
        float4 g3 = wq[wb0 + 3 * 256 + tid];
        float4 gx = {};
        if (tid < 32)
            gx = ((const float4*)xg)[((size_t)(bblk + (tid >> 1)) * IC + ig) * 2 + (tid & 1)];
        put(0, 0 * 256 + tid, g0);
        put(0, 1 * 256 + tid, g1);
        put(0, 2 * 256 + tid, g2);
        put(0, 3 * 256 + tid, g3);
        if (tid < 32) xs[0][tid] = gx;
    }

#pragma unroll 2
    for (int il = 0; il < IB; ++il) {
        const int p = il & 1;
        __syncthreads();   // tile(il) visible; everyone done with parity p^1

        // issue next tile's global loads immediately (latency under compute)
        float4 g0 = {}, g1 = {}, g2 = {}, g3 = {}, gx = {};
        const bool more = (il + 1 < IB);
        if (more) {
            const int ig = is * IB + il + 1;
            const size_t wb0 = (size_t)ig * 1024;
            g0 = wq[wb0 + 0 * 256 + tid];
            g1 = wq[wb0 + 1 * 256 + tid];
            g2 = wq[wb0 + 2 * 256 + tid];
            g3 = wq[wb0 + 3 * 256 + tid];
            if (tid < 32)
                gx = ((const float4*)xg)[((size_t)(bblk + (tid >> 1)) * IC + ig) * 2 + (tid & 1)];
        }

        // x fragments (broadcast LDS reads, wave-uniform addresses)
        float4 xa[4], xb[4];
#pragma unroll
        for (int n = 0; n < 4; ++n) {
            xa[n] = xs[p][(w * 4 + n) * 2];
            xb[n] = xs[p][(w * 4 + n) * 2 + 1];
        }

        // u_hat fragments: u[n][jj] = W[i,o,jh*8+jj,:] . x[b_n,i,:]
        float u[4][8];
#pragma unroll
        for (int jj = 0; jj < 8; ++jj) {
            const float4 wa = WA[p][jj * ROWQ + c];
            const float4 wbq = WB[p][jj * ROWQ + c];
#pragma unroll
            for (int n = 0; n < 4; ++n) {
                float t = wa.x * xa[n].x;
                t = fmaf(wa.y, xa[n].y, t);
                t = fmaf(wa.z, xa[n].z, t);
                t = fmaf(wa.w, xa[n].w, t);
                t = fmaf(wbq.x, xb[n].x, t);
                t = fmaf(wbq.y, xb[n].y, t);
                t = fmaf(wbq.z, xb[n].z, t);
                t = fmaf(wbq.w, xb[n].w, t);
                u[n][jj] = t;
            }
        }

        // routing coefficient + accumulate
#pragma unroll
        for (int n = 0; n < 4; ++n) {
            float cc;
            if (FIRST) {
                cc = 1.0f;  // softmax(0) = 1/32, folded into the store scale
            } else {
                float bp = u[n][0] * va[n].x;
                bp = fmaf(u[n][1], va[n].y, bp);
                bp = fmaf(u[n][2], va[n].z, bp);
                bp = fmaf(u[n][3], va[n].w, bp);
                bp = fmaf(u[n][4], vb[n].x, bp);
                bp = fmaf(u[n][5], vb[n].y, bp);
                bp = fmaf(u[n][6], vb[n].z, bp);
                bp = fmaf(u[n][7], vb[n].w, bp);
                bp += __shfl_xor(bp, 32);        // combine j-halves
                // no max-subtraction: |logit| is tiny, exp is safe in fp32
                const float e = __expf(bp);
                float se = e;
                se += __shfl_xor(se, 16);
                se += __shfl_xor(se, 8);
                se += __shfl_xor(se, 4);
                se += __shfl_xor(se, 2);
                se += __shfl_xor(se, 1);
                cc = e * __builtin_amdgcn_rcpf(se);
            }
#pragma unroll
            for (int jj = 0; jj < 8; ++jj)
                acc[n][jj] = fmaf(cc, u[n][jj], acc[n][jj]);
        }

        // drain staged tile into the other parity (race-free: barrier at top
        // of this iteration guarantees nobody still reads parity p^1)
        if (more) {
            put(p ^ 1, 0 * 256 + tid, g0);
            put(p ^ 1, 1 * 256 + tid, g1);
            put(p ^ 1, 2 * 256 + tid, g2);
            put(p ^ 1, 3 * 256 + tid, g3);
            if (tid < 32) xs[p ^ 1][tid] = gx;
        }
    }

    // disjoint per-(istripe, b) partials — no atomics, no memset needed
    const float scale = FIRST ? (1.0f / 32.0f) : 1.0f;
#pragma unroll
    for (int n = 0; n < 4; ++n) {
        float* dst = part + (size_t)is * S_ELEMS + (size_t)(bw + n) * (OC * OD) + o * OD + jh * 8;
        float4 lo = {acc[n][0] * scale, acc[n][1] * scale, acc[n][2] * scale, acc[n][3] * scale};
        float4 hi = {acc[n][4] * scale, acc[n][5] * scale, acc[n][6] * scale, acc[n][7] * scale};
        ((float4*)dst)[0] = lo;
        ((float4*)dst)[1] = hi;
    }
}

// Fused 128-way partial reduction + squash.
// MODE 0: vsum = v   MODE 1: vsum += v   MODE 2: out = v
template <int MODE>
__global__ void caps_reduce(const float* __restrict__ part,
                            float* __restrict__ vsum,
                            float* __restrict__ out)
{
    const int e = blockIdx.x * 256 + threadIdx.x;   // 0..32767 = (b,o,j)
    float s = 0.0f;
#pragma unroll 16
    for (int k = 0; k < ISTR; ++k)
        s += part[(size_t)k * S_ELEMS + e];
    float s2 = s * s;                // ||s||^2 over the 16 j's (16-lane group)
    s2 += __shfl_xor(s2, 1);
    s2 += __shfl_xor(s2, 2);
    s2 += __shfl_xor(s2, 4);
    s2 += __shfl_xor(s2, 8);
    const float v = s * (s2 / ((1.0f + s2) * sqrtf(s2 + 1e-9f)));
    if (MODE == 0)      vsum[e] = v;
    else if (MODE == 1) vsum[e] += v;
    else                out[e] = v;
}

extern "C" void kernel_launch(void* const* d_in, const int* in_sizes, int n_in,
                              void* d_out, int out_size, void* d_ws, size_t ws_size,
                              hipStream_t stream)
{
    const float* x = (const float*)d_in[0];   // [64, 2048, 8]
    const float* W = (const float*)d_in[1];   // [1, 2048, 32, 16, 8]
    float* out = (float*)d_out;               // [64, 32, 16]

    float* part = (float*)d_ws;                        // 128 x 32768 = 16 MB
    float* vsum = part + (size_t)ISTR * S_ELEMS;       // 32768 floats

    const dim3 g(BG * ISTR);      // 512 blocks
    const dim3 b(256);
    const dim3 rg(S_ELEMS / 256); // 128 blocks

    // round 0: c uniform
    caps_pass<1><<<g, b, 0, stream>>>(W, x, nullptr, part);
    caps_reduce<0><<<rg, b, 0, stream>>>(part, vsum, out);   // vsum = v0
    // round 1: b = u.v0
    caps_pass<0><<<g, b, 0, stream>>>(W, x, vsum, part);
    caps_reduce<1><<<rg, b, 0, stream>>>(part, vsum, out);   // vsum = v0+v1
    // round 2: b = u.(v0+v1)
    caps_pass<0><<<g, b, 0, stream>>>(W, x, vsum, part);
    caps_reduce<2><<<rg, b, 0, stream>>>(part, vsum, out);   // out = v2
}